// Round 1
// baseline (908.595 us; speedup 1.0000x reference)
//
#include <hip/hip_runtime.h>

// ---------------------------------------------------------------------------
// PositionalEncoding: out[b,l,d] = x[b,l,d] + pe[l,d]
//   counts = cumsum over l of TAB[rot[l], case[l]]          (exact small ints)
//   pe[l, 2k]   = sin(counts_x[l] * div_term[k])
//   pe[l, 2k+1] = cos(counts_y[l] * div_term[k])
// B=16, L=4096, D=2048.  Memory-bound: 0.5 GiB in + 0.5 GiB out.
// ---------------------------------------------------------------------------

#define B_  16
#define L_  4096
#define D_  2048
#define D4_ (D_ / 4)   // 512 float4 groups per row

__constant__ int c_TAB[8][5][2] = {
    { { 1,  0}, {-1,  0}, { 0, -1}, { 0,  1}, {0, 0} },
    { { 1,  1}, {-1, -1}, { 1, -1}, {-1,  1}, {0, 0} },
    { { 0,  1}, { 0, -1}, { 1,  0}, {-1,  0}, {0, 0} },
    { {-1,  1}, { 1, -1}, { 1,  1}, {-1, -1}, {0, 0} },
    { {-1,  0}, { 1,  0}, { 0,  1}, { 0, -1}, {0, 0} },
    { {-1, -1}, { 1,  1}, {-1,  1}, { 1, -1}, {0, 0} },
    { { 0, -1}, { 0,  1}, {-1,  0}, { 1,  0}, {0, 0} },
    { { 1, -1}, {-1,  1}, {-1, -1}, { 1,  1}, {0, 0} },
};

// ---------------------------------------------------------------------------
// Kernel 1: sequential-ish cumsum of deltas over L.  One block, 256 threads,
// 16 elements per thread.  Per-thread serial scan, Hillis-Steele block scan
// of per-thread sums in LDS, then write inclusive counts as float2.
// ---------------------------------------------------------------------------
__global__ __launch_bounds__(256) void scan_kernel(
    const int* __restrict__ action,   // (L, 3) int32
    float2* __restrict__ counts)      // (L,) float2  -> d_ws
{
    constexpr int NT = 256;
    constexpr int CHUNK = L_ / NT;    // 16
    __shared__ int2 sums[NT];

    const int t = threadIdx.x;
    const int base = t * CHUNK;

    int dx[CHUNK], dy[CHUNK];
    int sx = 0, sy = 0;
    #pragma unroll
    for (int j = 0; j < CHUNK; ++j) {
        const int l  = base + j;
        const int i0 = action[l * 3 + 0];
        const int i1 = action[l * 3 + 1];
        int r        = action[l * 3 + 2];
        r = ((r % 8) + 8) % 8;
        const int c = (i0 == 1) ? 0
                    : (i0 == -1) ? 1
                    : (i1 == 1) ? 2
                    : (i1 == -1) ? 3 : 4;
        sx += c_TAB[r][c][0];
        sy += c_TAB[r][c][1];
        dx[j] = sx;               // inclusive within this thread's chunk
        dy[j] = sy;
    }
    sums[t] = make_int2(sx, sy);
    __syncthreads();

    // Hillis-Steele inclusive scan over the 256 per-thread sums.
    for (int off = 1; off < NT; off <<= 1) {
        int2 v   = sums[t];
        int2 add = (t >= off) ? sums[t - off] : make_int2(0, 0);
        __syncthreads();
        sums[t] = make_int2(v.x + add.x, v.y + add.y);
        __syncthreads();
    }

    const int px = (t > 0) ? sums[t - 1].x : 0;
    const int py = (t > 0) ? sums[t - 1].y : 0;
    #pragma unroll
    for (int j = 0; j < CHUNK; ++j) {
        counts[base + j] = make_float2((float)(px + dx[j]), (float)(py + dy[j]));
    }
}

// ---------------------------------------------------------------------------
// Kernel 2: out = x + pe.  One thread per (l, d-quad); pe fragment computed
// once and reused across the 16 batches.  float4 loads/stores, coalesced.
// ---------------------------------------------------------------------------
__global__ __launch_bounds__(256) void pe_add_kernel(
    const float* __restrict__ x,          // (B, L, D)
    const float2* __restrict__ counts,    // (L,)  {cx, cy}
    const float2* __restrict__ div2,      // (D/2,) viewed as (D/4,) float2
    float* __restrict__ out)              // (B, L, D)
{
    const int tid = blockIdx.x * blockDim.x + threadIdx.x;   // [0, L*D/4)
    const int d4  = tid & (D4_ - 1);
    const int l   = tid >> 9;                                // tid / 512

    const float2 c  = counts[l];
    const float2 dt = div2[d4];   // div_term[2*d4], div_term[2*d4+1]

    // elements d=4*d4 .. d+3 -> k0 = 2*d4, k1 = 2*d4+1
    float4 pe;
    pe.x = sinf(c.x * dt.x);
    pe.y = cosf(c.y * dt.x);
    pe.z = sinf(c.x * dt.y);
    pe.w = cosf(c.y * dt.y);

    const size_t off         = (size_t)tid * 4;       // l*D + d
    const size_t batchStride = (size_t)L_ * D_;

    #pragma unroll 4
    for (int b = 0; b < B_; ++b) {
        const size_t idx = (size_t)b * batchStride + off;
        const float4 xv = *(const float4*)(x + idx);
        float4 ov;
        ov.x = xv.x + pe.x;
        ov.y = xv.y + pe.y;
        ov.z = xv.z + pe.z;
        ov.w = xv.w + pe.w;
        *(float4*)(out + idx) = ov;
    }
}

extern "C" void kernel_launch(void* const* d_in, const int* in_sizes, int n_in,
                              void* d_out, int out_size, void* d_ws, size_t ws_size,
                              hipStream_t stream) {
    const float* x        = (const float*)d_in[0];   // (16, 4096, 2048) fp32
    const int*   action   = (const int*)d_in[1];     // (4096, 3) int32
    const float* div_term = (const float*)d_in[2];   // (1024,) fp32
    float*       out      = (float*)d_out;
    float2*      counts   = (float2*)d_ws;           // 4096 * 8 B = 32 KiB

    scan_kernel<<<1, 256, 0, stream>>>(action, counts);

    const int total4 = (L_ * D_) / 4;                // 2,097,152 threads
    pe_add_kernel<<<total4 / 256, 256, 0, stream>>>(
        x, counts, (const float2*)div_term, out);
}